// Round 8
// baseline (74.665 us; speedup 1.0000x reference)
//
#include <hip/hip_runtime.h>
#include <math.h>

#define N_TOK 4096
#define HID 256
#define D_HEAD 32
#define N_HEADS 8
#define NSEG 4

typedef __bf16 bf16x8 __attribute__((ext_vector_type(8)));
typedef float f32x4 __attribute__((ext_vector_type(4)));
typedef unsigned short u16x8 __attribute__((ext_vector_type(8)));

static __device__ __forceinline__ unsigned short bf16_bits(float f) {
  __bf16 h = (__bf16)f;
  return __builtin_bit_cast(unsigned short, h);
}
static __device__ __forceinline__ float bf16_val(unsigned short u) {
  return (float)__builtin_bit_cast(__bf16, u);
}

// x pre-scaled by 2/ln2 (folded into Q projection): tanh = 1 - 2*r,
// r = 1/(1+2^x2). Trans-wave path: compute r only (exp2+add+rcp), fold
// "1-2*" via colsum-of-V MFMA + epilogue fma  [R5, verified].
static __device__ __forceinline__ float r_of(float x2) {
  float e = __builtin_amdgcn_exp2f(x2);
  return __builtin_amdgcn_rcpf(1.0f + e);
}

static __device__ __forceinline__ bf16x8 pack8(float4 a, float4 b) {
  bf16x8 v;
  v[0] = (__bf16)a.x; v[1] = (__bf16)a.y; v[2] = (__bf16)a.z; v[3] = (__bf16)a.w;
  v[4] = (__bf16)b.x; v[5] = (__bf16)b.y; v[6] = (__bf16)b.z; v[7] = (__bf16)b.w;
  return v;
}

// ---------------------------------------------------------------------------
// Kernel 0: one-time conversions + passthrough copy.
// ---------------------------------------------------------------------------
__global__ __launch_bounds__(256) void prep(
    const float* __restrict__ X,
    const float* __restrict__ Wq, const float* __restrict__ Wk,
    const float* __restrict__ Wv,
    float* __restrict__ out0, unsigned short* __restrict__ Xb,
    unsigned short* __restrict__ Wqb, unsigned short* __restrict__ Wkb,
    unsigned short* __restrict__ Wvb)
{
  const int b = blockIdx.x;
  const int tid = threadIdx.x;
  if (b < 512) {                       // X: 4096*256 f32, 8 per thread
    const size_t base = ((size_t)b * 256 + tid) * 8;
    float4 a = *(const float4*)(X + base);
    float4 c = *(const float4*)(X + base + 4);
    *(float4*)(out0 + base) = a;
    *(float4*)(out0 + base + 4) = c;
    *(bf16x8*)(Xb + base) = pack8(a, c);
  } else {                             // weights: 3 x 65536 f32
    const int r = b - 512;
    const int w = r >> 5;              // 0..2
    const float* W = (w == 0) ? Wq : (w == 1) ? Wk : Wv;
    unsigned short* O = (w == 0) ? Wqb : (w == 1) ? Wkb : Wvb;
    const size_t base = ((size_t)(r & 31) * 256 + tid) * 8;
    float4 a = *(const float4*)(W + base);
    float4 c = *(const float4*)(W + base + 4);
    *(bf16x8*)(O + base) = pack8(a, c);
  }
}

// ---------------------------------------------------------------------------
// Kernel 1: Q/K/V projections, bf16 inputs -> bf16 outputs.
// Q pre-scaled by 2/ln2. Q,K stored [head][n][32]; V stored
// transposed+slot-permuted so the PV MFMA A-frag is contiguous 16B/lane.
// ---------------------------------------------------------------------------
__global__ __launch_bounds__(256, 4) void proj_qkv(
    const unsigned short* __restrict__ Xb,
    const unsigned short* __restrict__ Wqb,
    const unsigned short* __restrict__ Wkb,
    const unsigned short* __restrict__ Wvb,
    unsigned short* __restrict__ Qws, unsigned short* __restrict__ Kws,
    unsigned short* __restrict__ Vws)
{
  const int lane = threadIdx.x & 63;
  const int wid  = threadIdx.x >> 6;
  const int lr = lane & 15, lg = lane >> 4;
  const int mb = blockIdx.x * 64 + (wid >> 1) * 32;
  const int ob = blockIdx.y * 64 + (wid & 1) * 32;
  const int z  = blockIdx.z;
  const unsigned short* W = (z == 0) ? Wqb : (z == 1) ? Wkb : Wvb;

  f32x4 acc[2][2];
#pragma unroll
  for (int i = 0; i < 2; ++i)
#pragma unroll
    for (int j = 0; j < 2; ++j) acc[i][j] = (f32x4){0.f, 0.f, 0.f, 0.f};

#pragma unroll 2
  for (int kb = 0; kb < HID; kb += 32) {
    bf16x8 af[2], bfr[2];
#pragma unroll
    for (int mi = 0; mi < 2; ++mi)
      af[mi] = *(const bf16x8*)(Xb + (size_t)(mb + mi * 16 + lr) * HID + kb + lg * 8);
#pragma unroll
    for (int oi = 0; oi < 2; ++oi)
      bfr[oi] = *(const bf16x8*)(W + (size_t)(ob + oi * 16 + lr) * HID + kb + lg * 8);
#pragma unroll
    for (int mi = 0; mi < 2; ++mi)
#pragma unroll
      for (int oi = 0; oi < 2; ++oi)
        acc[mi][oi] = __builtin_amdgcn_mfma_f32_16x16x32_bf16(
            af[mi], bfr[oi], acc[mi][oi], 0, 0, 0);
  }

  const float qscale = (z == 0) ? 2.885390081777927f : 1.0f;

  // C layout: col = lane&15, row = (lane>>4)*4 + r   [m89]
#pragma unroll
  for (int mi = 0; mi < 2; ++mi)
#pragma unroll
    for (int oi = 0; oi < 2; ++oi)
#pragma unroll
      for (int r = 0; r < 4; ++r) {
        const int n = mb + mi * 16 + lg * 4 + r;
        const int o = ob + oi * 16 + lr;
        const unsigned short bits = bf16_bits(acc[mi][oi][r] * qscale);
        const int h = o >> 5, d = o & 31;
        if (z < 2) {
          unsigned short* OUT = (z == 0) ? Qws : Kws;
          OUT[((size_t)h * N_TOK + n) * D_HEAD + d] = bits;
        } else {
          const int rr = n & 31;
          const int slot = (rr < 16) ? ((rr >> 2) * 8 + (rr & 3))
                                     : (((rr - 16) >> 2) * 8 + 4 + (rr & 3));
          Vws[(size_t)h * (N_TOK * D_HEAD) + (size_t)(n >> 5) * 1024 + d * 32 + slot] = bits;
        }
      }
}

// ---------------------------------------------------------------------------
// Kernel 2: per-head tanh attention — WAVE-SPECIALIZED dual path.
// 8 waves/block (512 thr), wid&3 = SIMD -> each SIMD hosts one TRANS wave
// (wid<4: r-form exp2+add+rcp, colsum-corrected) and one LUT wave (wid>=4:
// nearest-LUT tanh on the LDS pipe). In-order waves can't overlap the two
// pipes (R7 null); the SIMD scheduler across two specialized waves can:
// LUT lgkmcnt stalls are filled with trans issue and vice versa. Trans
// demand per SIMD halves vs R5; gather load halves vs R6. Path branch is
// scalar via readfirstlane. Wave owns 32 q rows; grid 512 x 512 thr.
// ---------------------------------------------------------------------------
struct Frags { bf16x8 k[2][2], v[2][2]; };

static __device__ __forceinline__ Frags load_phase(
    const unsigned short* __restrict__ Kh,
    const unsigned short* __restrict__ Vh, size_t base)
{
  Frags f;
#pragma unroll
  for (int s = 0; s < 2; ++s)
#pragma unroll
    for (int h = 0; h < 2; ++h) {
      f.k[s][h] = *(const bf16x8*)(Kh + base + s * 1024 + h * 512);
      f.v[s][h] = *(const bf16x8*)(Vh + base + s * 1024 + h * 512);
    }
  return f;
}

__global__ __launch_bounds__(512, 1) void attn_kernel(
    const unsigned short* __restrict__ Qws,
    const unsigned short* __restrict__ Kws,
    const unsigned short* __restrict__ Vws,
    unsigned short* __restrict__ part)
{
  __shared__ float tanh_tab[4640];                     // 18.1 KB LUT
  __shared__ __align__(16) float lds_t[8][16 * 36];    // epilogue transpose

  // LUT over prescaled score x2: entry i = tanh((i-2304)/512) of the RAW
  // score s; index from x2 via s*512 = x2*(ln2/2*512) = x2*177.445678.
  for (int i = threadIdx.x; i < 4609; i += 512)
    tanh_tab[i] = tanhf((float)(i - 2304) * (1.0f / 512.0f));
  __syncthreads();

  const int lane = threadIdx.x & 63;
  const int wid  = threadIdx.x >> 6;                   // 0..7
  const int wpath = __builtin_amdgcn_readfirstlane(wid); // scalar branch key
  const int b    = blockIdx.x;
  const int head = b & 7;            // blockIdx round-robin -> head pinned to XCD
  const int inner = b >> 3;          // 0..63
  const int qsplit = inner >> 2;     // 0..15
  const int seg    = inner & 3;      // 0..3
  const int qbase  = qsplit * 256 + wid * 32;   // 32 q rows per wave
  const int kstart = seg * (N_TOK / NSEG);      // 1024 keys per segment
  const int NT = (N_TOK / NSEG) / 64;           // 16 phases

  const unsigned short* Qh = Qws + (size_t)head * N_TOK * D_HEAD;
  const unsigned short* Kh = Kws + (size_t)head * N_TOK * D_HEAD;
  const unsigned short* Vh = Vws + (size_t)head * N_TOK * D_HEAD;

  const int lr = lane & 15, lg = lane >> 4;

  bf16x8 qf[2];
#pragma unroll
  for (int m = 0; m < 2; ++m)
    qf[m] = *(const bf16x8*)(Qh + (size_t)(qbase + m * 16 + lr) * 32 + lg * 8);

  const f32x4 z4 = {0.f, 0.f, 0.f, 0.f};
  f32x4 alo[2], ahi[2];
#pragma unroll
  for (int m = 0; m < 2; ++m) { alo[m] = z4; ahi[m] = z4; }

  // fragment base for phase t: fb + t*2048 (64 keys * 32 d elements/phase)
  const size_t fb = (size_t)kstart * 32 + lr * 32 + lg * 8;

  #define LUT_TANH(x2) ({                                                 \
    float _t = __builtin_fmaf((x2), 177.4456782f, 2304.5f);               \
    _t = __builtin_amdgcn_fmed3f(_t, 0.5f, 4608.5f);                      \
    tanh_tab[(int)_t]; })

  float* L = &lds_t[wid][0];
  const int qloc = lane >> 2, chunk = lane & 3;

  if (wpath < 4) {
    // ---------------- TRANS waves: r-form + colsum fold ----------------
    bf16x8 onesf;
#pragma unroll
    for (int j = 0; j < 8; ++j) onesf[j] = (__bf16)1.0f;
    f32x4 clo = z4, chi = z4;

    Frags fA = load_phase(Kh, Vh, fb);
    for (int t = 0; t < NT; t += 2) {
      Frags fB = load_phase(Kh, Vh, fb + (size_t)(t + 1) * 2048);
      __builtin_amdgcn_sched_barrier(0);
#pragma unroll
      for (int s = 0; s < 2; ++s) {
#pragma unroll
        for (int m = 0; m < 2; ++m) {
          f32x4 s0 = __builtin_amdgcn_mfma_f32_16x16x32_bf16(fA.k[s][0], qf[m], z4, 0, 0, 0);
          f32x4 s1 = __builtin_amdgcn_mfma_f32_16x16x32_bf16(fA.k[s][1], qf[m], z4, 0, 0, 0);
          bf16x8 pf;
#pragma unroll
          for (int r = 0; r < 4; ++r) pf[r]     = (__bf16)r_of(s0[r]);
#pragma unroll
          for (int r = 0; r < 4; ++r) pf[4 + r] = (__bf16)r_of(s1[r]);
          alo[m] = __builtin_amdgcn_mfma_f32_16x16x32_bf16(fA.v[s][0], pf, alo[m], 0, 0, 0);
          ahi[m] = __builtin_amdgcn_mfma_f32_16x16x32_bf16(fA.v[s][1], pf, ahi[m], 0, 0, 0);
        }
        clo = __builtin_amdgcn_mfma_f32_16x16x32_bf16(fA.v[s][0], onesf, clo, 0, 0, 0);
        chi = __builtin_amdgcn_mfma_f32_16x16x32_bf16(fA.v[s][1], onesf, chi, 0, 0, 0);
      }
      if (t + 2 < NT) fA = load_phase(Kh, Vh, fb + (size_t)(t + 2) * 2048);
      __builtin_amdgcn_sched_barrier(0);
#pragma unroll
      for (int s = 0; s < 2; ++s) {
#pragma unroll
        for (int m = 0; m < 2; ++m) {
          f32x4 s0 = __builtin_amdgcn_mfma_f32_16x16x32_bf16(fB.k[s][0], qf[m], z4, 0, 0, 0);
          f32x4 s1 = __builtin_amdgcn_mfma_f32_16x16x32_bf16(fB.k[s][1], qf[m], z4, 0, 0, 0);
          bf16x8 pf;
#pragma unroll
          for (int r = 0; r < 4; ++r) pf[r]     = (__bf16)r_of(s0[r]);
#pragma unroll
          for (int r = 0; r < 4; ++r) pf[4 + r] = (__bf16)r_of(s1[r]);
          alo[m] = __builtin_amdgcn_mfma_f32_16x16x32_bf16(fB.v[s][0], pf, alo[m], 0, 0, 0);
          ahi[m] = __builtin_amdgcn_mfma_f32_16x16x32_bf16(fB.v[s][1], pf, ahi[m], 0, 0, 0);
        }
        clo = __builtin_amdgcn_mfma_f32_16x16x32_bf16(fB.v[s][0], onesf, clo, 0, 0, 0);
        chi = __builtin_amdgcn_mfma_f32_16x16x32_bf16(fB.v[s][1], onesf, chi, 0, 0, 0);
      }
    }

    // epilogue: att = colsum - 2*acc, transpose via wave-private LDS
#pragma unroll
    for (int m = 0; m < 2; ++m) {
#pragma unroll
      for (int r = 0; r < 4; ++r) {
        L[lr * 36 + lg * 4 + r]      = __builtin_fmaf(alo[m][r], -2.0f, clo[r]);
        L[lr * 36 + 16 + lg * 4 + r] = __builtin_fmaf(ahi[m][r], -2.0f, chi[r]);
      }
      f32x4 va = *(const f32x4*)&L[qloc * 36 + chunk * 4];
      f32x4 vb = *(const f32x4*)&L[qloc * 36 + 16 + chunk * 4];
      ushort4 oa, ob;
      oa.x = bf16_bits(va[0]); oa.y = bf16_bits(va[1]);
      oa.z = bf16_bits(va[2]); oa.w = bf16_bits(va[3]);
      ob.x = bf16_bits(vb[0]); ob.y = bf16_bits(vb[1]);
      ob.z = bf16_bits(vb[2]); ob.w = bf16_bits(vb[3]);
      unsigned short* dst = part + ((size_t)seg * N_TOK + qbase + m * 16 + qloc) * HID
                          + head * 32 + chunk * 4;
      *(ushort4*)dst        = oa;
      *(ushort4*)(dst + 16) = ob;
    }
  } else {
    // ---------------- LUT waves: tanh direct from LDS table ----------------
    Frags fA = load_phase(Kh, Vh, fb);
    for (int t = 0; t < NT; t += 2) {
      Frags fB = load_phase(Kh, Vh, fb + (size_t)(t + 1) * 2048);
      __builtin_amdgcn_sched_barrier(0);
#pragma unroll
      for (int s = 0; s < 2; ++s)
#pragma unroll
        for (int m = 0; m < 2; ++m) {
          f32x4 s0 = __builtin_amdgcn_mfma_f32_16x16x32_bf16(fA.k[s][0], qf[m], z4, 0, 0, 0);
          f32x4 s1 = __builtin_amdgcn_mfma_f32_16x16x32_bf16(fA.k[s][1], qf[m], z4, 0, 0, 0);
          bf16x8 pf;
#pragma unroll
          for (int r = 0; r < 4; ++r) pf[r]     = (__bf16)LUT_TANH(s0[r]);
#pragma unroll
          for (int r = 0; r < 4; ++r) pf[4 + r] = (__bf16)LUT_TANH(s1[r]);
          alo[m] = __builtin_amdgcn_mfma_f32_16x16x32_bf16(fA.v[s][0], pf, alo[m], 0, 0, 0);
          ahi[m] = __builtin_amdgcn_mfma_f32_16x16x32_bf16(fA.v[s][1], pf, ahi[m], 0, 0, 0);
        }
      if (t + 2 < NT) fA = load_phase(Kh, Vh, fb + (size_t)(t + 2) * 2048);
      __builtin_amdgcn_sched_barrier(0);
#pragma unroll
      for (int s = 0; s < 2; ++s)
#pragma unroll
        for (int m = 0; m < 2; ++m) {
          f32x4 s0 = __builtin_amdgcn_mfma_f32_16x16x32_bf16(fB.k[s][0], qf[m], z4, 0, 0, 0);
          f32x4 s1 = __builtin_amdgcn_mfma_f32_16x16x32_bf16(fB.k[s][1], qf[m], z4, 0, 0, 0);
          bf16x8 pf;
#pragma unroll
          for (int r = 0; r < 4; ++r) pf[r]     = (__bf16)LUT_TANH(s0[r]);
#pragma unroll
          for (int r = 0; r < 4; ++r) pf[4 + r] = (__bf16)LUT_TANH(s1[r]);
          alo[m] = __builtin_amdgcn_mfma_f32_16x16x32_bf16(fB.v[s][0], pf, alo[m], 0, 0, 0);
          ahi[m] = __builtin_amdgcn_mfma_f32_16x16x32_bf16(fB.v[s][1], pf, ahi[m], 0, 0, 0);
        }
    }

    // epilogue: att = acc directly
#pragma unroll
    for (int m = 0; m < 2; ++m) {
#pragma unroll
      for (int r = 0; r < 4; ++r) {
        L[lr * 36 + lg * 4 + r]      = alo[m][r];
        L[lr * 36 + 16 + lg * 4 + r] = ahi[m][r];
      }
      f32x4 va = *(const f32x4*)&L[qloc * 36 + chunk * 4];
      f32x4 vb = *(const f32x4*)&L[qloc * 36 + 16 + chunk * 4];
      ushort4 oa, ob;
      oa.x = bf16_bits(va[0]); oa.y = bf16_bits(va[1]);
      oa.z = bf16_bits(va[2]); oa.w = bf16_bits(va[3]);
      ob.x = bf16_bits(vb[0]); ob.y = bf16_bits(vb[1]);
      ob.z = bf16_bits(vb[2]); ob.w = bf16_bits(vb[3]);
      unsigned short* dst = part + ((size_t)seg * N_TOK + qbase + m * 16 + qloc) * HID
                          + head * 32 + chunk * 4;
      *(ushort4*)dst        = oa;
      *(ushort4*)(dst + 16) = ob;
    }
  }
  #undef LUT_TANH
}

// ---------------------------------------------------------------------------
// Kernel 3: att_hidden = relu(att @ Wf^T + bf), f32 out.
// Full-width blocks: 256 blocks x 512 thr; seg-sum of each 16x256 A-tile
// computed ONCE (was twice with the (256,2) grid) -> PART read 16->8 MB,
// reduce-VALU halved. Same total wave count as before.
// ---------------------------------------------------------------------------
__global__ __launch_bounds__(512, 2) void final_proj(
    const unsigned short* __restrict__ part, const float* __restrict__ Wf,
    const float* __restrict__ bias, float* __restrict__ out)
{
  __shared__ __align__(16) unsigned short Alds[16][264];   // +8 pad: bank spread

  const int tid  = threadIdx.x;
  const int lane = tid & 63;
  const int wid  = tid >> 6;                 // 0..7
  const int lr = lane & 15, lg = lane >> 4;
  const int mb = blockIdx.x * 16;

  // cooperative seg-sum: 16 rows x 256 cols, thread t owns 8 elements
  {
    const int row = tid >> 5, c0 = (tid & 31) * 8;
    const size_t off = (size_t)(mb + row) * HID + c0;
    float s[8];
#pragma unroll
    for (int j = 0; j < 8; ++j) s[j] = 0.f;
#pragma unroll
    for (int sg = 0; sg < NSEG; ++sg) {
      u16x8 u = *(const u16x8*)(part + (size_t)sg * N_TOK * HID + off);
#pragma unroll
      for (int j = 0; j < 8; ++j) s[j] += bf16_val(u[j]);
    }
    bf16x8 o8;
#pragma unroll
    for (int j = 0; j < 8; ++j) o8[j] = (__bf16)s[j];
    *(bf16x8*)&Alds[row][c0] = o8;
  }
  __syncthreads();

  // wave w covers output cols [w*32, w*32+32): 2 col-tiles of 16
  f32x4 acc[2];
  acc[0] = (f32x4){0.f, 0.f, 0.f, 0.f};
  acc[1] = (f32x4){0.f, 0.f, 0.f, 0.f};

#pragma unroll 2
  for (int kb = 0; kb < HID; kb += 32) {
    bf16x8 af = *(const bf16x8*)&Alds[lr][kb + lg * 8];
#pragma unroll
    for (int y = 0; y < 2; ++y) {
      const int ob = wid * 32 + y * 16;
      const float* p = Wf + (size_t)(ob + lr) * HID + kb + lg * 8;
      bf16x8 bfr = pack8(*(const float4*)p, *(const float4*)(p + 4));
      acc[y] = __builtin_amdgcn_mfma_f32_16x16x32_bf16(af, bfr, acc[y], 0, 0, 0);
    }
  }

#pragma unroll
  for (int y = 0; y < 2; ++y)
#pragma unroll
    for (int r = 0; r < 4; ++r) {
      const int n = mb + lg * 4 + r;
      const int o = wid * 32 + y * 16 + lr;
      float v = acc[y][r] + bias[o];
      out[(size_t)n * HID + o] = fmaxf(v, 0.f);
    }
}

// ---------------------------------------------------------------------------
extern "C" void kernel_launch(void* const* d_in, const int* in_sizes, int n_in,
                              void* d_out, int out_size, void* d_ws, size_t ws_size,
                              hipStream_t stream)
{
  const float* X  = (const float*)d_in[0];
  const float* Wq = (const float*)d_in[1];
  const float* Wk = (const float*)d_in[2];
  const float* Wv = (const float*)d_in[3];
  const float* Wf = (const float*)d_in[4];
  const float* bf = (const float*)d_in[5];
  float* out = (float*)d_out;

  // ws layout: Q[0,2M) K[2,4M) V[4,6M) PART bf16 [6M,14M) = 14M total.
  // Xb (2M) + Wq/Wk/Wv bf16 (384K) OVERLAY the PART region: they are
  // consumed by proj_qkv before attn_kernel writes PART (stream-ordered).
  unsigned char* ws = (unsigned char*)d_ws;
  unsigned short* Qws  = (unsigned short*)(ws);
  unsigned short* Kws  = (unsigned short*)(ws + (2u << 20));
  unsigned short* Vws  = (unsigned short*)(ws + (4u << 20));
  unsigned short* PART = (unsigned short*)(ws + (6u << 20));
  unsigned short* Xb   = (unsigned short*)(ws + (6u << 20));
  unsigned short* Wqb  = (unsigned short*)(ws + (8u << 20));
  unsigned short* Wkb  = (unsigned short*)(ws + (8u << 20) + (128u << 10));
  unsigned short* Wvb  = (unsigned short*)(ws + (8u << 20) + (256u << 10));

  // prep also writes output 0 (passthrough of inputs) -> no memcpy dispatch
  prep<<<dim3(608), 256, 0, stream>>>(X, Wq, Wk, Wv, out, Xb, Wqb, Wkb, Wvb);
  proj_qkv<<<dim3(64, 4, 3), 256, 0, stream>>>(Xb, Wqb, Wkb, Wvb, Qws, Kws, Vws);
  attn_kernel<<<dim3(8 * 16 * NSEG), 512, 0, stream>>>(Qws, Kws, Vws, PART);
  final_proj<<<dim3(256), 512, 0, stream>>>(PART, Wf, bf, out + (size_t)N_TOK * HID);
}

// Round 9
// 70.086 us; speedup vs baseline: 1.0653x; 1.0653x over previous
//
#include <hip/hip_runtime.h>

#define N_TOK 4096
#define HID 256
#define D_HEAD 32
#define N_HEADS 8
#define NSEG 4

typedef __bf16 bf16x8 __attribute__((ext_vector_type(8)));
typedef float f32x4 __attribute__((ext_vector_type(4)));
typedef unsigned short u16x8 __attribute__((ext_vector_type(8)));

static __device__ __forceinline__ unsigned short bf16_bits(float f) {
  __bf16 h = (__bf16)f;
  return __builtin_bit_cast(unsigned short, h);
}
static __device__ __forceinline__ float bf16_val(unsigned short u) {
  return (float)__builtin_bit_cast(__bf16, u);
}

// x pre-scaled by 2/ln2 (folded into Q projection): tanh = 1 - 2*r,
// r = 1/(1+2^x2). Compute ONLY r (exp2 + add + rcp + cvt; the shortest
// chain — measured floor across 8 structural variants) and fold the
// "1 - 2*" into the PV accumulator via a colsum-of-V MFMA + epilogue fma:
//   sum_k tanh*v = colsum(V) - 2 * sum_k r*v        [R5, verified]
// Safe at extremes: x2->+inf: r=0 -> tanh=1; x2->-inf: r=1 -> tanh=-1.
static __device__ __forceinline__ float r_of(float x2) {
  float e = __builtin_amdgcn_exp2f(x2);
  return __builtin_amdgcn_rcpf(1.0f + e);
}

static __device__ __forceinline__ bf16x8 pack8(float4 a, float4 b) {
  bf16x8 v;
  v[0] = (__bf16)a.x; v[1] = (__bf16)a.y; v[2] = (__bf16)a.z; v[3] = (__bf16)a.w;
  v[4] = (__bf16)b.x; v[5] = (__bf16)b.y; v[6] = (__bf16)b.z; v[7] = (__bf16)b.w;
  return v;
}

// ---------------------------------------------------------------------------
// Kernel 0: one-time conversions + passthrough copy.
// ---------------------------------------------------------------------------
__global__ __launch_bounds__(256) void prep(
    const float* __restrict__ X,
    const float* __restrict__ Wq, const float* __restrict__ Wk,
    const float* __restrict__ Wv,
    float* __restrict__ out0, unsigned short* __restrict__ Xb,
    unsigned short* __restrict__ Wqb, unsigned short* __restrict__ Wkb,
    unsigned short* __restrict__ Wvb)
{
  const int b = blockIdx.x;
  const int tid = threadIdx.x;
  if (b < 512) {                       // X: 4096*256 f32, 8 per thread
    const size_t base = ((size_t)b * 256 + tid) * 8;
    float4 a = *(const float4*)(X + base);
    float4 c = *(const float4*)(X + base + 4);
    *(float4*)(out0 + base) = a;
    *(float4*)(out0 + base + 4) = c;
    *(bf16x8*)(Xb + base) = pack8(a, c);
  } else {                             // weights: 3 x 65536 f32
    const int r = b - 512;
    const int w = r >> 5;              // 0..2
    const float* W = (w == 0) ? Wq : (w == 1) ? Wk : Wv;
    unsigned short* O = (w == 0) ? Wqb : (w == 1) ? Wkb : Wvb;
    const size_t base = ((size_t)(r & 31) * 256 + tid) * 8;
    float4 a = *(const float4*)(W + base);
    float4 c = *(const float4*)(W + base + 4);
    *(bf16x8*)(O + base) = pack8(a, c);
  }
}

// ---------------------------------------------------------------------------
// Kernel 1: Q/K/V projections, bf16 inputs -> bf16 outputs.
// Q pre-scaled by 2/ln2. Q,K stored [head][n][32]; V stored
// transposed+slot-permuted so the PV MFMA A-frag is contiguous 16B/lane.
// ---------------------------------------------------------------------------
__global__ __launch_bounds__(256, 4) void proj_qkv(
    const unsigned short* __restrict__ Xb,
    const unsigned short* __restrict__ Wqb,
    const unsigned short* __restrict__ Wkb,
    const unsigned short* __restrict__ Wvb,
    unsigned short* __restrict__ Qws, unsigned short* __restrict__ Kws,
    unsigned short* __restrict__ Vws)
{
  const int lane = threadIdx.x & 63;
  const int wid  = threadIdx.x >> 6;
  const int lr = lane & 15, lg = lane >> 4;
  const int mb = blockIdx.x * 64 + (wid >> 1) * 32;
  const int ob = blockIdx.y * 64 + (wid & 1) * 32;
  const int z  = blockIdx.z;
  const unsigned short* W = (z == 0) ? Wqb : (z == 1) ? Wkb : Wvb;

  f32x4 acc[2][2];
#pragma unroll
  for (int i = 0; i < 2; ++i)
#pragma unroll
    for (int j = 0; j < 2; ++j) acc[i][j] = (f32x4){0.f, 0.f, 0.f, 0.f};

#pragma unroll 2
  for (int kb = 0; kb < HID; kb += 32) {
    bf16x8 af[2], bfr[2];
#pragma unroll
    for (int mi = 0; mi < 2; ++mi)
      af[mi] = *(const bf16x8*)(Xb + (size_t)(mb + mi * 16 + lr) * HID + kb + lg * 8);
#pragma unroll
    for (int oi = 0; oi < 2; ++oi)
      bfr[oi] = *(const bf16x8*)(W + (size_t)(ob + oi * 16 + lr) * HID + kb + lg * 8);
#pragma unroll
    for (int mi = 0; mi < 2; ++mi)
#pragma unroll
      for (int oi = 0; oi < 2; ++oi)
        acc[mi][oi] = __builtin_amdgcn_mfma_f32_16x16x32_bf16(
            af[mi], bfr[oi], acc[mi][oi], 0, 0, 0);
  }

  const float qscale = (z == 0) ? 2.885390081777927f : 1.0f;

  // C layout: col = lane&15, row = (lane>>4)*4 + r   [m89]
#pragma unroll
  for (int mi = 0; mi < 2; ++mi)
#pragma unroll
    for (int oi = 0; oi < 2; ++oi)
#pragma unroll
      for (int r = 0; r < 4; ++r) {
        const int n = mb + mi * 16 + lg * 4 + r;
        const int o = ob + oi * 16 + lr;
        const unsigned short bits = bf16_bits(acc[mi][oi][r] * qscale);
        const int h = o >> 5, d = o & 31;
        if (z < 2) {
          unsigned short* OUT = (z == 0) ? Qws : Kws;
          OUT[((size_t)h * N_TOK + n) * D_HEAD + d] = bits;
        } else {
          const int rr = n & 31;
          const int slot = (rr < 16) ? ((rr >> 2) * 8 + (rr & 3))
                                     : (((rr - 16) >> 2) * 8 + 4 + (rr & 3));
          Vws[(size_t)h * (N_TOK * D_HEAD) + (size_t)(n >> 5) * 1024 + d * 32 + slot] = bits;
        }
      }
}

// ---------------------------------------------------------------------------
// Kernel 2: per-head tanh attention — R5-exact (session best, ~38us).
// NO K/V LDS staging (L2-resident per (head,seg), head pinned to XCD via
// b&7); fragments global->register, double-buffered with static names;
// barrier-free main loop. Per score: exp2+add+rcp+cvt (measured floor);
// "1-2r" folded via colsum-of-V MFMA on the matrix pipe + epilogue fma.
// Geometry sweet spot (measured): NSEG=4, 64 q-rows/wave, grid 512 =
// 2 blocks/CU = 2 waves/SIMD; any NSEG cut halves occupancy or doubles
// K/V traffic (R3: +4%).
// ---------------------------------------------------------------------------
struct Frags { bf16x8 k[2][2], v[2][2]; };

static __device__ __forceinline__ Frags load_phase(
    const unsigned short* __restrict__ Kh,
    const unsigned short* __restrict__ Vh, size_t base)
{
  Frags f;
#pragma unroll
  for (int s = 0; s < 2; ++s)
#pragma unroll
    for (int h = 0; h < 2; ++h) {
      f.k[s][h] = *(const bf16x8*)(Kh + base + s * 1024 + h * 512);
      f.v[s][h] = *(const bf16x8*)(Vh + base + s * 1024 + h * 512);
    }
  return f;
}

__global__ __launch_bounds__(256, 2) void attn_kernel(
    const unsigned short* __restrict__ Qws,
    const unsigned short* __restrict__ Kws,
    const unsigned short* __restrict__ Vws,
    unsigned short* __restrict__ part)
{
  __shared__ __align__(16) float lds_t[4][16 * 36];    // epilogue transpose only

  const int lane = threadIdx.x & 63;
  const int wid  = threadIdx.x >> 6;
  const int b    = blockIdx.x;
  const int head = b & 7;            // blockIdx round-robin -> head pinned to XCD
  const int inner = b >> 3;          // 0..63
  const int qsplit = inner >> 2;     // 0..15
  const int seg    = inner & 3;      // 0..3
  const int qbase  = qsplit * 256 + wid * 64;   // 64 q rows per wave
  const int kstart = seg * (N_TOK / NSEG);      // 1024 keys per segment
  const int NT = (N_TOK / NSEG) / 64;           // 16 phases

  const unsigned short* Qh = Qws + (size_t)head * N_TOK * D_HEAD;
  const unsigned short* Kh = Kws + (size_t)head * N_TOK * D_HEAD;
  const unsigned short* Vh = Vws + (size_t)head * N_TOK * D_HEAD;

  const int lr = lane & 15, lg = lane >> 4;

  bf16x8 qf[4];
#pragma unroll
  for (int m = 0; m < 4; ++m)
    qf[m] = *(const bf16x8*)(Qh + (size_t)(qbase + m * 16 + lr) * 32 + lg * 8);

  bf16x8 onesf;
#pragma unroll
  for (int j = 0; j < 8; ++j) onesf[j] = (__bf16)1.0f;

  const f32x4 z4 = {0.f, 0.f, 0.f, 0.f};
  f32x4 alo[4], ahi[4];
#pragma unroll
  for (int m = 0; m < 4; ++m) { alo[m] = z4; ahi[m] = z4; }
  f32x4 clo = z4, chi = z4;            // colsum(V) accumulators (d-major)

  // fragment base for phase t: fb + t*2048 (64 keys * 32 d elements/phase)
  const size_t fb = (size_t)kstart * 32 + lr * 32 + lg * 8;

  Frags fA = load_phase(Kh, Vh, fb);

  for (int t = 0; t < NT; t += 2) {
    Frags fB = load_phase(Kh, Vh, fb + (size_t)(t + 1) * 2048);
    __builtin_amdgcn_sched_barrier(0);   // pin B-issue before A-compute

#pragma unroll
    for (int s = 0; s < 2; ++s) {
#pragma unroll
      for (int m = 0; m < 4; ++m) {
        f32x4 s0 = __builtin_amdgcn_mfma_f32_16x16x32_bf16(fA.k[s][0], qf[m], z4, 0, 0, 0);
        f32x4 s1 = __builtin_amdgcn_mfma_f32_16x16x32_bf16(fA.k[s][1], qf[m], z4, 0, 0, 0);
        bf16x8 pf;
#pragma unroll
        for (int r = 0; r < 4; ++r) pf[r]     = (__bf16)r_of(s0[r]);
#pragma unroll
        for (int r = 0; r < 4; ++r) pf[4 + r] = (__bf16)r_of(s1[r]);
        alo[m] = __builtin_amdgcn_mfma_f32_16x16x32_bf16(fA.v[s][0], pf, alo[m], 0, 0, 0);
        ahi[m] = __builtin_amdgcn_mfma_f32_16x16x32_bf16(fA.v[s][1], pf, ahi[m], 0, 0, 0);
      }
      clo = __builtin_amdgcn_mfma_f32_16x16x32_bf16(fA.v[s][0], onesf, clo, 0, 0, 0);
      chi = __builtin_amdgcn_mfma_f32_16x16x32_bf16(fA.v[s][1], onesf, chi, 0, 0, 0);
    }

    if (t + 2 < NT) fA = load_phase(Kh, Vh, fb + (size_t)(t + 2) * 2048);
    __builtin_amdgcn_sched_barrier(0);   // pin A-issue before B-compute

#pragma unroll
    for (int s = 0; s < 2; ++s) {
#pragma unroll
      for (int m = 0; m < 4; ++m) {
        f32x4 s0 = __builtin_amdgcn_mfma_f32_16x16x32_bf16(fB.k[s][0], qf[m], z4, 0, 0, 0);
        f32x4 s1 = __builtin_amdgcn_mfma_f32_16x16x32_bf16(fB.k[s][1], qf[m], z4, 0, 0, 0);
        bf16x8 pf;
#pragma unroll
        for (int r = 0; r < 4; ++r) pf[r]     = (__bf16)r_of(s0[r]);
#pragma unroll
        for (int r = 0; r < 4; ++r) pf[4 + r] = (__bf16)r_of(s1[r]);
        alo[m] = __builtin_amdgcn_mfma_f32_16x16x32_bf16(fB.v[s][0], pf, alo[m], 0, 0, 0);
        ahi[m] = __builtin_amdgcn_mfma_f32_16x16x32_bf16(fB.v[s][1], pf, ahi[m], 0, 0, 0);
      }
      clo = __builtin_amdgcn_mfma_f32_16x16x32_bf16(fB.v[s][0], onesf, clo, 0, 0, 0);
      chi = __builtin_amdgcn_mfma_f32_16x16x32_bf16(fB.v[s][1], onesf, chi, 0, 0, 0);
    }
  }

  // epilogue: att = colsum - 2*acc, transpose (d-major regs) -> [q][d]
  // rows via wave-private LDS; store bf16 partials coalesced. No barrier:
  // within-wave program order.
  float* L = &lds_t[wid][0];
  const int qloc = lane >> 2, chunk = lane & 3;
#pragma unroll
  for (int m = 0; m < 4; ++m) {
#pragma unroll
    for (int r = 0; r < 4; ++r) {
      L[lr * 36 + lg * 4 + r]      = __builtin_fmaf(alo[m][r], -2.0f, clo[r]);
      L[lr * 36 + 16 + lg * 4 + r] = __builtin_fmaf(ahi[m][r], -2.0f, chi[r]);
    }
    f32x4 va = *(const f32x4*)&L[qloc * 36 + chunk * 4];
    f32x4 vb = *(const f32x4*)&L[qloc * 36 + 16 + chunk * 4];
    ushort4 oa, ob;
    oa.x = bf16_bits(va[0]); oa.y = bf16_bits(va[1]);
    oa.z = bf16_bits(va[2]); oa.w = bf16_bits(va[3]);
    ob.x = bf16_bits(vb[0]); ob.y = bf16_bits(vb[1]);
    ob.z = bf16_bits(vb[2]); ob.w = bf16_bits(vb[3]);
    unsigned short* dst = part + ((size_t)seg * N_TOK + qbase + m * 16 + qloc) * HID
                        + head * 32 + chunk * 4;
    *(ushort4*)dst        = oa;
    *(ushort4*)(dst + 16) = ob;
  }
}

// ---------------------------------------------------------------------------
// Kernel 3: att_hidden = relu(att @ Wf^T + bf), f32 out.
// Full-width blocks: 256 blocks x 512 thr; seg-sum of each 16x256 A-tile
// computed ONCE (PART read 8MB instead of 16MB, reduce-VALU halved).
// ---------------------------------------------------------------------------
__global__ __launch_bounds__(512, 2) void final_proj(
    const unsigned short* __restrict__ part, const float* __restrict__ Wf,
    const float* __restrict__ bias, float* __restrict__ out)
{
  __shared__ __align__(16) unsigned short Alds[16][264];   // +8 pad: bank spread

  const int tid  = threadIdx.x;
  const int lane = tid & 63;
  const int wid  = tid >> 6;                 // 0..7
  const int lr = lane & 15, lg = lane >> 4;
  const int mb = blockIdx.x * 16;

  // cooperative seg-sum: 16 rows x 256 cols, thread t owns 8 elements
  {
    const int row = tid >> 5, c0 = (tid & 31) * 8;
    const size_t off = (size_t)(mb + row) * HID + c0;
    float s[8];
#pragma unroll
    for (int j = 0; j < 8; ++j) s[j] = 0.f;
#pragma unroll
    for (int sg = 0; sg < NSEG; ++sg) {
      u16x8 u = *(const u16x8*)(part + (size_t)sg * N_TOK * HID + off);
#pragma unroll
      for (int j = 0; j < 8; ++j) s[j] += bf16_val(u[j]);
    }
    bf16x8 o8;
#pragma unroll
    for (int j = 0; j < 8; ++j) o8[j] = (__bf16)s[j];
    *(bf16x8*)&Alds[row][c0] = o8;
  }
  __syncthreads();

  // wave w covers output cols [w*32, w*32+32): 2 col-tiles of 16
  f32x4 acc[2];
  acc[0] = (f32x4){0.f, 0.f, 0.f, 0.f};
  acc[1] = (f32x4){0.f, 0.f, 0.f, 0.f};

#pragma unroll 2
  for (int kb = 0; kb < HID; kb += 32) {
    bf16x8 af = *(const bf16x8*)&Alds[lr][kb + lg * 8];
#pragma unroll
    for (int y = 0; y < 2; ++y) {
      const int ob = wid * 32 + y * 16;
      const float* p = Wf + (size_t)(ob + lr) * HID + kb + lg * 8;
      bf16x8 bfr = pack8(*(const float4*)p, *(const float4*)(p + 4));
      acc[y] = __builtin_amdgcn_mfma_f32_16x16x32_bf16(af, bfr, acc[y], 0, 0, 0);
    }
  }

#pragma unroll
  for (int y = 0; y < 2; ++y)
#pragma unroll
    for (int r = 0; r < 4; ++r) {
      const int n = mb + lg * 4 + r;
      const int o = wid * 32 + y * 16 + lr;
      float v = acc[y][r] + bias[o];
      out[(size_t)n * HID + o] = fmaxf(v, 0.f);
    }
}

// ---------------------------------------------------------------------------
extern "C" void kernel_launch(void* const* d_in, const int* in_sizes, int n_in,
                              void* d_out, int out_size, void* d_ws, size_t ws_size,
                              hipStream_t stream)
{
  const float* X  = (const float*)d_in[0];
  const float* Wq = (const float*)d_in[1];
  const float* Wk = (const float*)d_in[2];
  const float* Wv = (const float*)d_in[3];
  const float* Wf = (const float*)d_in[4];
  const float* bf = (const float*)d_in[5];
  float* out = (float*)d_out;

  // ws layout: Q[0,2M) K[2,4M) V[4,6M) PART bf16 [6M,14M) = 14M total.
  // Xb (2M) + Wq/Wk/Wv bf16 (384K) OVERLAY the PART region: they are
  // consumed by proj_qkv before attn_kernel writes PART (stream-ordered).
  unsigned char* ws = (unsigned char*)d_ws;
  unsigned short* Qws  = (unsigned short*)(ws);
  unsigned short* Kws  = (unsigned short*)(ws + (2u << 20));
  unsigned short* Vws  = (unsigned short*)(ws + (4u << 20));
  unsigned short* PART = (unsigned short*)(ws + (6u << 20));
  unsigned short* Xb   = (unsigned short*)(ws + (6u << 20));
  unsigned short* Wqb  = (unsigned short*)(ws + (8u << 20));
  unsigned short* Wkb  = (unsigned short*)(ws + (8u << 20) + (128u << 10));
  unsigned short* Wvb  = (unsigned short*)(ws + (8u << 20) + (256u << 10));

  // prep also writes output 0 (passthrough of inputs) -> no memcpy dispatch
  prep<<<dim3(608), 256, 0, stream>>>(X, Wq, Wk, Wv, out, Xb, Wqb, Wkb, Wvb);
  proj_qkv<<<dim3(64, 4, 3), 256, 0, stream>>>(Xb, Wqb, Wkb, Wvb, Qws, Kws, Vws);
  attn_kernel<<<dim3(8 * 16 * NSEG), 256, 0, stream>>>(Qws, Kws, Vws, PART);
  final_proj<<<dim3(256), 512, 0, stream>>>(PART, Wf, bf, out + (size_t)N_TOK * HID);
}